// Round 7
// baseline (342.029 us; speedup 1.0000x reference)
//
#include <hip/hip_runtime.h>
#include <cstdint>

// ---------------------------------------------------------------------------
// GCN graph classification on MI355X (gfx950), v7.
//   deg8 (XCD-priv) -> reduce -> cj,ci,row_start,cursor8; CSR fill
//   xb  = bf16(cj * x)
//   a1[n] = sum_{e: dst=n} xb[src]                   (SpMM row-sum, F=128)
//   h1t8  = bf16(cj * relu((a1 @ W1) * ci + b1))     (MFMA GEMM, k-blocked store)
//   Wg[g][s] = sum_{e: gid[dst]=g, src=s} ci[dst]    (graph-local atomics, XCD-pinned)
//   tpart[b] = Wg[:, kchunk_b] @ h1[kchunk_b, :]     (dense MFMA, no atomics)
//   out[g] = (sum_b tpart)[g] @ (W2@Wl)/cnt + (b2@Wl + bl)
// ---------------------------------------------------------------------------

typedef __attribute__((ext_vector_type(8))) short short8v;
typedef __attribute__((ext_vector_type(4))) float f32x4;

static __device__ __forceinline__ unsigned short f2bf(float f) {
  unsigned u = __float_as_uint(f);
  u += 0x7FFFu + ((u >> 16) & 1u);   // RTNE
  return (unsigned short)(u >> 16);
}
static __device__ __forceinline__ float bf2f(unsigned short h) {
  return __uint_as_float(((unsigned)h) << 16);
}

// XCD-local degree histograms: copy x=blockIdx%8 only touched by ~1 XCD.
__global__ void k_degrees(const int* __restrict__ src, const int* __restrict__ dst,
                          int* __restrict__ outdeg8, int* __restrict__ indeg8,
                          int E, int N) {
  int i = blockIdx.x * blockDim.x + threadIdx.x;
  int x = blockIdx.x & 7;
  if (i < E) {
    atomicAdd(&outdeg8[(size_t)x * N + src[i]], 1);
    atomicAdd(&indeg8[(size_t)x * N + dst[i]], 1);
  }
}

// Reduce 8 copies -> cj/ci/indeg_tot, row_start (wave-scan + bump), cursor8.
__global__ void k_norms(const int* __restrict__ outdeg8, const int* __restrict__ indeg8,
                        float* __restrict__ cj, float* __restrict__ ci,
                        int* __restrict__ indeg_tot, int* __restrict__ row_start,
                        int* __restrict__ cursor8, int* __restrict__ counter, int N) {
  int i = blockIdx.x * blockDim.x + threadIdx.x;
  int din = 0, dout = 0;
  int dx[8];
  if (i < N) {
#pragma unroll
    for (int x = 0; x < 8; ++x) {
      dx[x] = indeg8[(size_t)x * N + i];
      din += dx[x];
      dout += outdeg8[(size_t)x * N + i];
    }
    cj[i] = rsqrtf((float)(dout > 1 ? dout : 1));
    ci[i] = rsqrtf((float)(din  > 1 ? din  : 1));
    indeg_tot[i] = din;
  }
  int lane = threadIdx.x & 63;
  int inc = din;
#pragma unroll
  for (int off = 1; off < 64; off <<= 1) {
    int o = __shfl_up(inc, off);
    if (lane >= off) inc += o;
  }
  int excl = inc - din;
  int wsum = __shfl(inc, 63);
  int base = 0;
  if (lane == 0) base = atomicAdd(counter, wsum);
  base = __shfl(base, 0);
  if (i < N) {
    int rs = base + excl;
    row_start[i] = rs;
#pragma unroll
    for (int x = 0; x < 8; ++x) {
      cursor8[(size_t)x * N + i] = rs;
      rs += dx[x];
    }
  }
}

// CSR fill with XCD-local cursors (same edge->block mapping as k_degrees).
__global__ void k_fill(const int* __restrict__ src, const int* __restrict__ dst,
                       int* __restrict__ cursor8, int* __restrict__ csr_src,
                       int E, int N) {
  int i = blockIdx.x * blockDim.x + threadIdx.x;
  int x = blockIdx.x & 7;
  if (i < E) {
    int d = dst[i];
    int pos = atomicAdd(&cursor8[(size_t)x * N + d], 1);
    csr_src[pos] = src[i];
  }
}

// f32 -> bf16 cast with per-row cj scale; 4 elements/thread, rows of 128.
__global__ void k_cast_scale(const float4* __restrict__ x, const float* __restrict__ cj,
                             unsigned short* __restrict__ o, int n4) {
  int i = blockIdx.x * blockDim.x + threadIdx.x;
  if (i < n4) {
    float c = cj[i >> 5];            // 32 float4 per 128-wide row
    float4 v = x[i];
    uint2 r;
    r.x = (unsigned)f2bf(c * v.x) | ((unsigned)f2bf(c * v.y) << 16);
    r.y = (unsigned)f2bf(c * v.z) | ((unsigned)f2bf(c * v.w) << 16);
    *(uint2*)(o + (size_t)i * 4) = r;
  }
}

// W[K][Nn] f32 -> BT[Nn][K] bf16 (transpose + cast; tiny).
__global__ void k_castT(const float* __restrict__ W, unsigned short* __restrict__ BT,
                        int K, int Nn) {
  int i = blockIdx.x * blockDim.x + threadIdx.x;
  if (i < K * Nn) {
    int k = i / Nn, nn = i - k * Nn;
    BT[(size_t)nn * K + k] = f2bf(W[i]);
  }
}

// Pure row-sum gather: one 64-thread block per destination node, unroll-4 ILP.
__global__ void k_spmm(const unsigned* __restrict__ feat,
                       const int* __restrict__ row_start, const int* __restrict__ cnts,
                       const int* __restrict__ csr_src, unsigned* __restrict__ out, int N) {
  int n = blockIdx.x;
  if (n >= N) return;
  int beg = row_start[n];
  int cnt = cnts[n];
  int t = threadIdx.x;
  float acc0 = 0.f, acc1 = 0.f;

  int k = 0;
  for (; k + 4 <= cnt; k += 4) {
    int s0 = csr_src[beg + k + 0];
    int s1 = csr_src[beg + k + 1];
    int s2 = csr_src[beg + k + 2];
    int s3 = csr_src[beg + k + 3];
    unsigned w0 = feat[(size_t)s0 * 64 + t];
    unsigned w1 = feat[(size_t)s1 * 64 + t];
    unsigned w2 = feat[(size_t)s2 * 64 + t];
    unsigned w3 = feat[(size_t)s3 * 64 + t];
    acc0 += bf2f((unsigned short)(w0 & 0xFFFF)) + bf2f((unsigned short)(w1 & 0xFFFF))
          + bf2f((unsigned short)(w2 & 0xFFFF)) + bf2f((unsigned short)(w3 & 0xFFFF));
    acc1 += bf2f((unsigned short)(w0 >> 16)) + bf2f((unsigned short)(w1 >> 16))
          + bf2f((unsigned short)(w2 >> 16)) + bf2f((unsigned short)(w3 >> 16));
  }
  for (; k < cnt; ++k) {
    int s = csr_src[beg + k];
    unsigned w = feat[(size_t)s * 64 + t];
    acc0 += bf2f((unsigned short)(w & 0xFFFF));
    acc1 += bf2f((unsigned short)(w >> 16));
  }
  out[(size_t)n * 64 + t] = (unsigned)f2bf(acc0) | ((unsigned)f2bf(acc1) << 16);
}

// MFMA GEMM1: h1 = f(A[M,128] @ W1), written in k-blocked layout
// h1t8[(row/8)*2048 + col*8 + (row&7)]  (B-fragment order for k_tgemm).
// Block: 4 waves, 128 rows x 256 cols; B staged in LDS; A preloaded.
__global__ __launch_bounds__(256, 2)
void k_gemm_mfma(const unsigned short* __restrict__ A, const unsigned short* __restrict__ BT,
                 const float* __restrict__ ci, const float* __restrict__ bias,
                 const float* __restrict__ cjv, unsigned short* __restrict__ out, int M) {
  constexpr int K = 128;
  __shared__ unsigned short Bs[64 * 64 * 8];   // 64 frags x 64 lanes x 8 bf16 = 64KB
  const int tid = threadIdx.x;
  const int lane = tid & 63;
  const int wave = tid >> 6;
  const int l15 = lane & 15;
  const int kA = (lane >> 4) * 8;

  // Stage B: frag f = kb*16+ct holds BT[ct*16+(l&15)][kb*32+(l>>4)*8 + j]
#pragma unroll
  for (int it = 0; it < 16; ++it) {
    int c = it * 256 + tid;
    int f = c >> 6, l = c & 63;
    int ct = f & 15, kb = f >> 4;
    int col = ct * 16 + (l & 15);
    int ko = kb * 32 + (l >> 4) * 8;
    *(uint4*)&Bs[(size_t)c * 8] = *(const uint4*)(BT + (size_t)col * K + ko);
  }
  __syncthreads();

  const int rowW = blockIdx.x * 128 + wave * 32;
  const unsigned short* aP0 = A + (size_t)(rowW + l15) * K + kA;
  const unsigned short* aP1 = aP0 + (size_t)16 * K;

  short8v a0[4], a1[4];
#pragma unroll
  for (int kb = 0; kb < 4; ++kb) {
    a0[kb] = *(const short8v*)(aP0 + kb * 32);
    a1[kb] = *(const short8v*)(aP1 + kb * 32);
  }

  f32x4 acc0[16], acc1[16];
#pragma unroll
  for (int i = 0; i < 16; ++i) {
    acc0[i] = (f32x4){0.f, 0.f, 0.f, 0.f};
    acc1[i] = (f32x4){0.f, 0.f, 0.f, 0.f};
  }

  const unsigned short* bL = Bs + lane * 8;
#pragma unroll
  for (int kb = 0; kb < 4; ++kb) {
#pragma unroll
    for (int ct = 0; ct < 16; ++ct) {
      short8v bv = *(const short8v*)(bL + (size_t)(kb * 16 + ct) * 512);
      acc0[ct] = __builtin_amdgcn_mfma_f32_16x16x32_bf16(a0[kb], bv, acc0[ct], 0, 0, 0);
      acc1[ct] = __builtin_amdgcn_mfma_f32_16x16x32_bf16(a1[kb], bv, acc1[ct], 0, 0, 0);
    }
  }

  // Epilogue: 4 consecutive rows per thread -> one 8B store in k-blocked layout.
#pragma unroll
  for (int half = 0; half < 2; ++half) {
    const f32x4* acc = half ? acc1 : acc0;
    const int row0 = rowW + (lane >> 4) * 4 + half * 16;   // multiple of 4
    float cir[4], cjr[4];
#pragma unroll
    for (int r = 0; r < 4; ++r) {
      int rI = row0 + r; if (rI > M - 1) rI = M - 1;
      cir[r] = ci[rI];
      cjr[r] = cjv[rI];
    }
    unsigned short* ob = out + (size_t)(row0 >> 3) * 2048 + (row0 & 7);
#pragma unroll
    for (int ct = 0; ct < 16; ++ct) {
      int col = ct * 16 + l15;
      float bb = bias[col];
      unsigned h0 = f2bf(fmaxf(acc[ct][0] * cir[0] + bb, 0.f) * cjr[0]);
      unsigned h1 = f2bf(fmaxf(acc[ct][1] * cir[1] + bb, 0.f) * cjr[1]);
      unsigned h2 = f2bf(fmaxf(acc[ct][2] * cir[2] + bb, 0.f) * cjr[2]);
      unsigned h3 = f2bf(fmaxf(acc[ct][3] * cir[3] + bb, 0.f) * cjr[3]);
      uint2 pk;
      pk.x = h0 | (h1 << 16);
      pk.y = h2 | (h3 << 16);
      *(uint2*)(ob + (size_t)col * 8) = pk;
    }
  }
}

// Wg[g][s] += ci[n] for each in-edge (s->n) of graph g. Blocks of the same g
// satisfy blockIdx % 8 == g % 8 (G multiple of 8) -> same XCD -> row's atomic
// lines stay in one L2 (no cross-XCD ping-pong). gid sorted -> binary search.
__global__ void k_wgn2(const int* __restrict__ gids, const float* __restrict__ ci,
                       const int* __restrict__ row_start, const int* __restrict__ cnts,
                       const int* __restrict__ csr_src, float* __restrict__ Wg,
                       int N, int Npad, int G) {
  int g = blockIdx.x % G;
  int sub = blockIdx.x / G;      // 0..7
  int lo = 0, hi = N;
  while (lo < hi) { int m = (lo + hi) >> 1; if (gids[m] < g) lo = m + 1; else hi = m; }
  int lo2 = lo, hi2 = N;
  while (lo2 < hi2) { int m = (lo2 + hi2) >> 1; if (gids[m] < g + 1) lo2 = m + 1; else hi2 = m; }
  int len = lo2 - lo;
  int nb = lo + (int)(((long long)len * sub) >> 3);
  int ne = lo + (int)(((long long)len * (sub + 1)) >> 3);
  float* wrow = Wg + (size_t)g * Npad;
  for (int n = nb + (int)threadIdx.x; n < ne; n += (int)blockDim.x) {
    float cin = ci[n];
    int beg = row_start[n];
    int cnt = cnts[n];
    for (int k = 0; k < cnt; ++k)
      atomicAdd(&wrow[csr_src[beg + k]], cin);
  }
}

// tpart[blk] = bf16(Wg[:, kchunk]) @ h1[kchunk, :]; K-chunk 256 per block.
// A chunk staged in LDS as bf16; B read from h1t8 (k-blocked); plain stores.
__global__ __launch_bounds__(256)
void k_tgemm(const float* __restrict__ Wg, const unsigned short* __restrict__ h1t8,
             float* __restrict__ tpart, int Npad) {
  __shared__ unsigned short As[64][136];
  const int tid = threadIdx.x;
  const int lane = tid & 63;
  const int wv = tid >> 6;
  const int l15 = lane & 15;
  const int kA = (lane >> 4) * 8;

  f32x4 acc[16];
#pragma unroll
  for (int i = 0; i < 16; ++i) acc[i] = (f32x4){0.f, 0.f, 0.f, 0.f};

  const int kbeg = blockIdx.x * 256;
#pragma unroll
  for (int step = 0; step < 2; ++step) {
    int k0 = kbeg + step * 128;
    if (k0 >= Npad) break;
    // stage A chunk [64 g][128 k] f32 -> bf16 LDS
#pragma unroll
    for (int it = 0; it < 8; ++it) {
      int idx = it * 256 + tid;          // 2048 float4
      int r = idx >> 5, q = idx & 31;
      float4 v = *(const float4*)(Wg + (size_t)r * Npad + k0 + q * 4);
      uint2 pk;
      pk.x = (unsigned)f2bf(v.x) | ((unsigned)f2bf(v.y) << 16);
      pk.y = (unsigned)f2bf(v.z) | ((unsigned)f2bf(v.w) << 16);
      *(uint2*)&As[r][q * 4] = pk;
    }
    __syncthreads();
#pragma unroll
    for (int sub = 0; sub < 4; ++sub) {
      short8v a[4];
#pragma unroll
      for (int m = 0; m < 4; ++m)
        a[m] = *(const short8v*)&As[m * 16 + l15][sub * 32 + kA];
      int kk = k0 + sub * 32 + kA;
      const unsigned short* bp = h1t8 + (size_t)(kk >> 3) * 2048;
#pragma unroll
      for (int n = 0; n < 4; ++n) {
        int col = wv * 64 + n * 16 + l15;
        short8v bv = *(const short8v*)(bp + (size_t)col * 8);
#pragma unroll
        for (int m = 0; m < 4; ++m)
          acc[m * 4 + n] = __builtin_amdgcn_mfma_f32_16x16x32_bf16(a[m], bv, acc[m * 4 + n], 0, 0, 0);
      }
    }
    __syncthreads();
  }

  float* tp = tpart + (size_t)blockIdx.x * 16384;
  const int grp = lane >> 4;
#pragma unroll
  for (int m = 0; m < 4; ++m)
#pragma unroll
    for (int n = 0; n < 4; ++n) {
      int col = wv * 64 + n * 16 + l15;
      f32x4 v = acc[m * 4 + n];
#pragma unroll
      for (int r = 0; r < 4; ++r)
        tp[(size_t)(m * 16 + grp * 4 + r) * 256 + col] = v[r];
    }
}

// Wc = W2 @ Wl  [256][L]; cb = b2 @ Wl + bl  [L]
__global__ void k_prep(const float* __restrict__ W2, const float* __restrict__ Wl,
                       const float* __restrict__ b2, const float* __restrict__ bl,
                       float* __restrict__ Wc, float* __restrict__ cb, int L) {
  int c = blockIdx.x;
  int l = threadIdx.x;
  if (l >= L) return;
  if (c < 256) {
    float a = 0.f;
    for (int m = 0; m < 256; ++m) a += W2[(size_t)c * 256 + m] * Wl[(size_t)m * L + l];
    Wc[(size_t)c * L + l] = a;
  } else {
    float a = bl[l];
    for (int m = 0; m < 256; ++m) a += b2[m] * Wl[(size_t)m * L + l];
    cb[l] = a;
  }
}

// out[g][l] = (sum_b tpart[b])[g] @ Wc / max(cnt,1) + (cnt>0 ? cb : bl)
__global__ __launch_bounds__(256)
void k_final(const float* __restrict__ tpart, const int* __restrict__ gids,
             const float* __restrict__ Wc, const float* __restrict__ cb,
             const float* __restrict__ bl, float* __restrict__ out,
             int N, int L, int NB) {
  int g = blockIdx.x;
  __shared__ float ts[256];
  int c = threadIdx.x;
  float s = 0.f;
  for (int b = 0; b < NB; ++b) s += tpart[(size_t)b * 16384 + g * 256 + c];
  ts[c] = s;
  int lo = 0, hi = N;
  while (lo < hi) { int m = (lo + hi) >> 1; if (gids[m] < g) lo = m + 1; else hi = m; }
  int lo2 = lo, hi2 = N;
  while (lo2 < hi2) { int m = (lo2 + hi2) >> 1; if (gids[m] < g + 1) lo2 = m + 1; else hi2 = m; }
  int cnt = lo2 - lo;
  float inv = 1.0f / (float)(cnt > 1 ? cnt : 1);
  __syncthreads();
  if (c < L) {
    float a = 0.f;
    for (int k = 0; k < 256; ++k) a += ts[k] * Wc[(size_t)k * L + c];
    out[(size_t)g * L + c] = a * inv + (cnt > 0 ? cb[c] : bl[c]);
  }
}

static inline size_t alignup(size_t v) { return (v + 255) & ~(size_t)255; }

extern "C" void kernel_launch(void* const* d_in, const int* in_sizes, int n_in,
                              void* d_out, int out_size, void* d_ws, size_t ws_size,
                              hipStream_t stream) {
  const float* x   = (const float*)d_in[0];
  const int*   src = (const int*)d_in[1];
  const int*   dst = (const int*)d_in[2];
  const int*   gid = (const int*)d_in[3];
  const float* W1  = (const float*)d_in[5];
  const float* b1  = (const float*)d_in[6];
  const float* W2  = (const float*)d_in[7];
  const float* b2  = (const float*)d_in[8];
  const float* Wl  = (const float*)d_in[9];
  const float* bl  = (const float*)d_in[10];
  float* out = (float*)d_out;

  const int N  = in_sizes[3];        // 50000
  const int E  = in_sizes[1];        // 800000
  const int L  = in_sizes[10];       // 50
  const int G  = out_size / L;       // 64
  const int RB = (N + 127) / 128;    // GEMM1 row blocks
  const int Npad = RB * 128;         // 50048
  const int NB = (Npad + 255) / 256; // tgemm K-chunks (196)

  char* p = (char*)d_ws;
  int*   outdeg8  = (int*)p;   p += alignup((size_t)8 * N * 4);
  int*   indeg8   = (int*)p;   p += alignup((size_t)8 * N * 4);
  float* Wg       = (float*)p; p += alignup((size_t)G * Npad * 4);
  int*   counter  = (int*)p;   p += 256;
  size_t zero_bytes = (size_t)(p - (char*)d_ws);
  int*   indeg_tot= (int*)p;   p += alignup((size_t)N * 4);
  int*   cursor8  = (int*)p;   p += alignup((size_t)8 * N * 4);
  float* cj       = (float*)p; p += alignup((size_t)N * 4);
  float* ci       = (float*)p; p += alignup((size_t)N * 4);
  int*   row_start= (int*)p;   p += alignup((size_t)N * 4);
  int*   csr_src  = (int*)p;   p += alignup((size_t)E * 4);
  unsigned short* xb   = (unsigned short*)p; p += alignup((size_t)Npad * 128 * 2);
  unsigned short* a1   = (unsigned short*)p; p += alignup((size_t)Npad * 128 * 2);
  unsigned short* h1t8 = (unsigned short*)p; p += alignup((size_t)Npad * 256 * 2);
  unsigned short* BT1  = (unsigned short*)p; p += alignup((size_t)256 * 128 * 2);
  float* tpart    = (float*)p; p += alignup((size_t)NB * 64 * 256 * 4);
  float* Wc       = (float*)p; p += alignup((size_t)256 * L * 4);
  float* cb       = (float*)p; p += alignup((size_t)L * 4);
  (void)ws_size; (void)n_in;

  hipMemsetAsync(d_ws, 0, zero_bytes, stream);

  k_degrees<<<(E + 255) / 256, 256, 0, stream>>>(src, dst, outdeg8, indeg8, E, N);
  k_norms<<<(N + 255) / 256, 256, 0, stream>>>(outdeg8, indeg8, cj, ci, indeg_tot,
                                               row_start, cursor8, counter, N);
  k_fill<<<(E + 255) / 256, 256, 0, stream>>>(src, dst, cursor8, csr_src, E, N);

  k_castT<<<(128 * 256 + 255) / 256, 256, 0, stream>>>(W1, BT1, 128, 256);
  k_cast_scale<<<(N * 128 / 4 + 255) / 256, 256, 0, stream>>>((const float4*)x, cj, xb,
                                                              N * 128 / 4);
  k_prep<<<257, 64, 0, stream>>>(W2, Wl, b2, bl, Wc, cb, L);

  k_spmm<<<N, 64, 0, stream>>>((const unsigned*)xb, row_start, indeg_tot, csr_src,
                               (unsigned*)a1, N);

  k_gemm_mfma<<<RB, 256, 0, stream>>>(a1, BT1, ci, b1, cj, h1t8, N);

  k_wgn2<<<8 * G, 256, 0, stream>>>(gid, ci, row_start, indeg_tot, csr_src, Wg, N, Npad, G);

  k_tgemm<<<NB, 256, 0, stream>>>(Wg, h1t8, tpart, Npad);

  k_final<<<G, 256, 0, stream>>>(tpart, gid, Wc, cb, bl, out, N, L, NB);
}

// Round 8
// 298.776 us; speedup vs baseline: 1.1448x; 1.1448x over previous
//
#include <hip/hip_runtime.h>
#include <cstdint>

// ---------------------------------------------------------------------------
// GCN graph classification on MI355X (gfx950), v8.
//   deg8 (XCD-priv) -> reduce -> cj,ci,row_start,cursor8; CSR fill
//   xb  = bf16(cj * x)
//   a1[n] = sum_{e: dst=n} xb[src]                   (SpMM row-sum, F=128)
//   h1t8  = bf16(cj * relu((a1 @ W1) * ci + b1))     (MFMA GEMM, k-blocked store)
//   Wg[g][s] = sum_{e: gid[dst]=g, src=s} ci[dst]    (graph-local atomics, XCD-pinned)
//   tpart[b] = Wg[:, kchunk_b] @ h1[kchunk_b, :]     (dense MFMA, no atomics)
//   t = sum_b tpart[b]                               (parallel tree reduce, XCD-pinned)
//   out[g] = t[g] @ (W2@Wl)/cnt + (b2@Wl + bl)
// ---------------------------------------------------------------------------

typedef __attribute__((ext_vector_type(8))) short short8v;
typedef __attribute__((ext_vector_type(4))) float f32x4;

static __device__ __forceinline__ unsigned short f2bf(float f) {
  unsigned u = __float_as_uint(f);
  u += 0x7FFFu + ((u >> 16) & 1u);   // RTNE
  return (unsigned short)(u >> 16);
}
static __device__ __forceinline__ float bf2f(unsigned short h) {
  return __uint_as_float(((unsigned)h) << 16);
}

// XCD-local degree histograms: copy x=blockIdx%8 only touched by ~1 XCD.
__global__ void k_degrees(const int* __restrict__ src, const int* __restrict__ dst,
                          int* __restrict__ outdeg8, int* __restrict__ indeg8,
                          int E, int N) {
  int i = blockIdx.x * blockDim.x + threadIdx.x;
  int x = blockIdx.x & 7;
  if (i < E) {
    atomicAdd(&outdeg8[(size_t)x * N + src[i]], 1);
    atomicAdd(&indeg8[(size_t)x * N + dst[i]], 1);
  }
}

// Reduce 8 copies -> cj/ci/indeg_tot, row_start (wave-scan + bump), cursor8.
__global__ void k_norms(const int* __restrict__ outdeg8, const int* __restrict__ indeg8,
                        float* __restrict__ cj, float* __restrict__ ci,
                        int* __restrict__ indeg_tot, int* __restrict__ row_start,
                        int* __restrict__ cursor8, int* __restrict__ counter, int N) {
  int i = blockIdx.x * blockDim.x + threadIdx.x;
  int din = 0, dout = 0;
  int dx[8];
  if (i < N) {
#pragma unroll
    for (int x = 0; x < 8; ++x) {
      dx[x] = indeg8[(size_t)x * N + i];
      din += dx[x];
      dout += outdeg8[(size_t)x * N + i];
    }
    cj[i] = rsqrtf((float)(dout > 1 ? dout : 1));
    ci[i] = rsqrtf((float)(din  > 1 ? din  : 1));
    indeg_tot[i] = din;
  }
  int lane = threadIdx.x & 63;
  int inc = din;
#pragma unroll
  for (int off = 1; off < 64; off <<= 1) {
    int o = __shfl_up(inc, off);
    if (lane >= off) inc += o;
  }
  int excl = inc - din;
  int wsum = __shfl(inc, 63);
  int base = 0;
  if (lane == 0) base = atomicAdd(counter, wsum);
  base = __shfl(base, 0);
  if (i < N) {
    int rs = base + excl;
    row_start[i] = rs;
#pragma unroll
    for (int x = 0; x < 8; ++x) {
      cursor8[(size_t)x * N + i] = rs;
      rs += dx[x];
    }
  }
}

// CSR fill with XCD-local cursors (same edge->block mapping as k_degrees).
__global__ void k_fill(const int* __restrict__ src, const int* __restrict__ dst,
                       int* __restrict__ cursor8, int* __restrict__ csr_src,
                       int E, int N) {
  int i = blockIdx.x * blockDim.x + threadIdx.x;
  int x = blockIdx.x & 7;
  if (i < E) {
    int d = dst[i];
    int pos = atomicAdd(&cursor8[(size_t)x * N + d], 1);
    csr_src[pos] = src[i];
  }
}

// f32 -> bf16 cast with per-row cj scale; 4 elements/thread, rows of 128.
__global__ void k_cast_scale(const float4* __restrict__ x, const float* __restrict__ cj,
                             unsigned short* __restrict__ o, int n4) {
  int i = blockIdx.x * blockDim.x + threadIdx.x;
  if (i < n4) {
    float c = cj[i >> 5];            // 32 float4 per 128-wide row
    float4 v = x[i];
    uint2 r;
    r.x = (unsigned)f2bf(c * v.x) | ((unsigned)f2bf(c * v.y) << 16);
    r.y = (unsigned)f2bf(c * v.z) | ((unsigned)f2bf(c * v.w) << 16);
    *(uint2*)(o + (size_t)i * 4) = r;
  }
}

// W[K][Nn] f32 -> BT[Nn][K] bf16 (transpose + cast; tiny).
__global__ void k_castT(const float* __restrict__ W, unsigned short* __restrict__ BT,
                        int K, int Nn) {
  int i = blockIdx.x * blockDim.x + threadIdx.x;
  if (i < K * Nn) {
    int k = i / Nn, nn = i - k * Nn;
    BT[(size_t)nn * K + k] = f2bf(W[i]);
  }
}

// Pure row-sum gather: one 64-thread block per destination node, unroll-4 ILP.
__global__ void k_spmm(const unsigned* __restrict__ feat,
                       const int* __restrict__ row_start, const int* __restrict__ cnts,
                       const int* __restrict__ csr_src, unsigned* __restrict__ out, int N) {
  int n = blockIdx.x;
  if (n >= N) return;
  int beg = row_start[n];
  int cnt = cnts[n];
  int t = threadIdx.x;
  float acc0 = 0.f, acc1 = 0.f;

  int k = 0;
  for (; k + 4 <= cnt; k += 4) {
    int s0 = csr_src[beg + k + 0];
    int s1 = csr_src[beg + k + 1];
    int s2 = csr_src[beg + k + 2];
    int s3 = csr_src[beg + k + 3];
    unsigned w0 = feat[(size_t)s0 * 64 + t];
    unsigned w1 = feat[(size_t)s1 * 64 + t];
    unsigned w2 = feat[(size_t)s2 * 64 + t];
    unsigned w3 = feat[(size_t)s3 * 64 + t];
    acc0 += bf2f((unsigned short)(w0 & 0xFFFF)) + bf2f((unsigned short)(w1 & 0xFFFF))
          + bf2f((unsigned short)(w2 & 0xFFFF)) + bf2f((unsigned short)(w3 & 0xFFFF));
    acc1 += bf2f((unsigned short)(w0 >> 16)) + bf2f((unsigned short)(w1 >> 16))
          + bf2f((unsigned short)(w2 >> 16)) + bf2f((unsigned short)(w3 >> 16));
  }
  for (; k < cnt; ++k) {
    int s = csr_src[beg + k];
    unsigned w = feat[(size_t)s * 64 + t];
    acc0 += bf2f((unsigned short)(w & 0xFFFF));
    acc1 += bf2f((unsigned short)(w >> 16));
  }
  out[(size_t)n * 64 + t] = (unsigned)f2bf(acc0) | ((unsigned)f2bf(acc1) << 16);
}

// MFMA GEMM1: h1 = f(A[M,128] @ W1), written in k-blocked layout
// h1t8[(row/8)*2048 + col*8 + (row&7)]  (B-fragment order for k_tgemm).
// Block: 4 waves, 128 rows x 256 cols; B staged in LDS; A preloaded.
__global__ __launch_bounds__(256, 2)
void k_gemm_mfma(const unsigned short* __restrict__ A, const unsigned short* __restrict__ BT,
                 const float* __restrict__ ci, const float* __restrict__ bias,
                 const float* __restrict__ cjv, unsigned short* __restrict__ out, int M) {
  constexpr int K = 128;
  __shared__ unsigned short Bs[64 * 64 * 8];   // 64 frags x 64 lanes x 8 bf16 = 64KB
  const int tid = threadIdx.x;
  const int lane = tid & 63;
  const int wave = tid >> 6;
  const int l15 = lane & 15;
  const int kA = (lane >> 4) * 8;

  // Stage B: frag f = kb*16+ct holds BT[ct*16+(l&15)][kb*32+(l>>4)*8 + j]
#pragma unroll
  for (int it = 0; it < 16; ++it) {
    int c = it * 256 + tid;
    int f = c >> 6, l = c & 63;
    int ct = f & 15, kb = f >> 4;
    int col = ct * 16 + (l & 15);
    int ko = kb * 32 + (l >> 4) * 8;
    *(uint4*)&Bs[(size_t)c * 8] = *(const uint4*)(BT + (size_t)col * K + ko);
  }
  __syncthreads();

  const int rowW = blockIdx.x * 128 + wave * 32;
  const unsigned short* aP0 = A + (size_t)(rowW + l15) * K + kA;
  const unsigned short* aP1 = aP0 + (size_t)16 * K;

  short8v a0[4], a1[4];
#pragma unroll
  for (int kb = 0; kb < 4; ++kb) {
    a0[kb] = *(const short8v*)(aP0 + kb * 32);
    a1[kb] = *(const short8v*)(aP1 + kb * 32);
  }

  f32x4 acc0[16], acc1[16];
#pragma unroll
  for (int i = 0; i < 16; ++i) {
    acc0[i] = (f32x4){0.f, 0.f, 0.f, 0.f};
    acc1[i] = (f32x4){0.f, 0.f, 0.f, 0.f};
  }

  const unsigned short* bL = Bs + lane * 8;
#pragma unroll
  for (int kb = 0; kb < 4; ++kb) {
#pragma unroll
    for (int ct = 0; ct < 16; ++ct) {
      short8v bv = *(const short8v*)(bL + (size_t)(kb * 16 + ct) * 512);
      acc0[ct] = __builtin_amdgcn_mfma_f32_16x16x32_bf16(a0[kb], bv, acc0[ct], 0, 0, 0);
      acc1[ct] = __builtin_amdgcn_mfma_f32_16x16x32_bf16(a1[kb], bv, acc1[ct], 0, 0, 0);
    }
  }

  // Epilogue: 4 consecutive rows per thread -> one 8B store in k-blocked layout.
#pragma unroll
  for (int half = 0; half < 2; ++half) {
    const f32x4* acc = half ? acc1 : acc0;
    const int row0 = rowW + (lane >> 4) * 4 + half * 16;   // multiple of 4
    float cir[4], cjr[4];
#pragma unroll
    for (int r = 0; r < 4; ++r) {
      int rI = row0 + r; if (rI > M - 1) rI = M - 1;
      cir[r] = ci[rI];
      cjr[r] = cjv[rI];
    }
    unsigned short* ob = out + (size_t)(row0 >> 3) * 2048 + (row0 & 7);
#pragma unroll
    for (int ct = 0; ct < 16; ++ct) {
      int col = ct * 16 + l15;
      float bb = bias[col];
      unsigned h0 = f2bf(fmaxf(acc[ct][0] * cir[0] + bb, 0.f) * cjr[0]);
      unsigned h1 = f2bf(fmaxf(acc[ct][1] * cir[1] + bb, 0.f) * cjr[1]);
      unsigned h2 = f2bf(fmaxf(acc[ct][2] * cir[2] + bb, 0.f) * cjr[2]);
      unsigned h3 = f2bf(fmaxf(acc[ct][3] * cir[3] + bb, 0.f) * cjr[3]);
      uint2 pk;
      pk.x = h0 | (h1 << 16);
      pk.y = h2 | (h3 << 16);
      *(uint2*)(ob + (size_t)col * 8) = pk;
    }
  }
}

// Wg[g][s] += ci[n] for each in-edge (s->n) of graph g. Blocks of the same g
// satisfy blockIdx % 8 == g % 8 (G multiple of 8) -> same XCD -> row's atomic
// lines stay in one L2 (no cross-XCD ping-pong). gid sorted -> binary search.
__global__ void k_wgn2(const int* __restrict__ gids, const float* __restrict__ ci,
                       const int* __restrict__ row_start, const int* __restrict__ cnts,
                       const int* __restrict__ csr_src, float* __restrict__ Wg,
                       int N, int Npad, int G) {
  int g = blockIdx.x % G;
  int sub = blockIdx.x / G;      // 0..7
  int lo = 0, hi = N;
  while (lo < hi) { int m = (lo + hi) >> 1; if (gids[m] < g) lo = m + 1; else hi = m; }
  int lo2 = lo, hi2 = N;
  while (lo2 < hi2) { int m = (lo2 + hi2) >> 1; if (gids[m] < g + 1) lo2 = m + 1; else hi2 = m; }
  int len = lo2 - lo;
  int nb = lo + (int)(((long long)len * sub) >> 3);
  int ne = lo + (int)(((long long)len * (sub + 1)) >> 3);
  float* wrow = Wg + (size_t)g * Npad;
  for (int n = nb + (int)threadIdx.x; n < ne; n += (int)blockDim.x) {
    float cin = ci[n];
    int beg = row_start[n];
    int cnt = cnts[n];
    for (int k = 0; k < cnt; ++k)
      atomicAdd(&wrow[csr_src[beg + k]], cin);
  }
}

// tpart[blk] = bf16(Wg[:, kchunk]) @ h1[kchunk, :]; K-chunk 256 per block.
// A chunk staged in LDS as bf16; B read from h1t8 (k-blocked); plain stores.
__global__ __launch_bounds__(256)
void k_tgemm(const float* __restrict__ Wg, const unsigned short* __restrict__ h1t8,
             float* __restrict__ tpart, int Npad) {
  __shared__ unsigned short As[64][136];
  const int tid = threadIdx.x;
  const int lane = tid & 63;
  const int wv = tid >> 6;
  const int l15 = lane & 15;
  const int kA = (lane >> 4) * 8;

  f32x4 acc[16];
#pragma unroll
  for (int i = 0; i < 16; ++i) acc[i] = (f32x4){0.f, 0.f, 0.f, 0.f};

  const int kbeg = blockIdx.x * 256;
#pragma unroll
  for (int step = 0; step < 2; ++step) {
    int k0 = kbeg + step * 128;
    if (k0 >= Npad) break;
    // stage A chunk [64 g][128 k] f32 -> bf16 LDS
#pragma unroll
    for (int it = 0; it < 8; ++it) {
      int idx = it * 256 + tid;          // 2048 float4
      int r = idx >> 5, q = idx & 31;
      float4 v = *(const float4*)(Wg + (size_t)r * Npad + k0 + q * 4);
      uint2 pk;
      pk.x = (unsigned)f2bf(v.x) | ((unsigned)f2bf(v.y) << 16);
      pk.y = (unsigned)f2bf(v.z) | ((unsigned)f2bf(v.w) << 16);
      *(uint2*)&As[r][q * 4] = pk;
    }
    __syncthreads();
#pragma unroll
    for (int sub = 0; sub < 4; ++sub) {
      short8v a[4];
#pragma unroll
      for (int m = 0; m < 4; ++m)
        a[m] = *(const short8v*)&As[m * 16 + l15][sub * 32 + kA];
      int kk = k0 + sub * 32 + kA;
      const unsigned short* bp = h1t8 + (size_t)(kk >> 3) * 2048;
#pragma unroll
      for (int n = 0; n < 4; ++n) {
        int col = wv * 64 + n * 16 + l15;
        short8v bv = *(const short8v*)(bp + (size_t)col * 8);
#pragma unroll
        for (int m = 0; m < 4; ++m)
          acc[m * 4 + n] = __builtin_amdgcn_mfma_f32_16x16x32_bf16(a[m], bv, acc[m * 4 + n], 0, 0, 0);
      }
    }
    __syncthreads();
  }

  float* tp = tpart + (size_t)blockIdx.x * 16384;
  const int grp = lane >> 4;
#pragma unroll
  for (int m = 0; m < 4; ++m)
#pragma unroll
    for (int n = 0; n < 4; ++n) {
      int col = wv * 64 + n * 16 + l15;
      f32x4 v = acc[m * 4 + n];
#pragma unroll
      for (int r = 0; r < 4; ++r)
        tp[(size_t)(m * 16 + grp * 4 + r) * 256 + col] = v[r];
    }
}

// Parallel reduce tpart -> t. bid = chunk*64 + g, so bid%8 == g%8: all blocks
// of row g land on the same XCD -> t-row atomic lines stay in one L2.
__global__ __launch_bounds__(256)
void k_tred(const float* __restrict__ tpart, float* __restrict__ t, int NB, int NCH) {
  int g = blockIdx.x & 63;
  int chunk = blockIdx.x >> 6;
  int c = threadIdx.x;
  float s = 0.f;
  for (int b = chunk; b < NB; b += NCH)
    s += tpart[(size_t)b * 16384 + g * 256 + c];
  atomicAdd(&t[(size_t)g * 256 + c], s);
}

// Wc = W2 @ Wl  [256][L]; cb = b2 @ Wl + bl  [L]
__global__ void k_prep(const float* __restrict__ W2, const float* __restrict__ Wl,
                       const float* __restrict__ b2, const float* __restrict__ bl,
                       float* __restrict__ Wc, float* __restrict__ cb, int L) {
  int c = blockIdx.x;
  int l = threadIdx.x;
  if (l >= L) return;
  if (c < 256) {
    float a = 0.f;
    for (int m = 0; m < 256; ++m) a += W2[(size_t)c * 256 + m] * Wl[(size_t)m * L + l];
    Wc[(size_t)c * L + l] = a;
  } else {
    float a = bl[l];
    for (int m = 0; m < 256; ++m) a += b2[m] * Wl[(size_t)m * L + l];
    cb[l] = a;
  }
}

// out[g][l] = t[g] @ Wc / max(cnt,1) + (cnt>0 ? cb : bl)
__global__ __launch_bounds__(256)
void k_final2(const float* __restrict__ t, const int* __restrict__ gids,
              const float* __restrict__ Wc, const float* __restrict__ cb,
              const float* __restrict__ bl, float* __restrict__ out,
              int N, int L) {
  int g = blockIdx.x;
  __shared__ float ts[256];
  int c = threadIdx.x;
  ts[c] = t[(size_t)g * 256 + c];
  int lo = 0, hi = N;
  while (lo < hi) { int m = (lo + hi) >> 1; if (gids[m] < g) lo = m + 1; else hi = m; }
  int lo2 = lo, hi2 = N;
  while (lo2 < hi2) { int m = (lo2 + hi2) >> 1; if (gids[m] < g + 1) lo2 = m + 1; else hi2 = m; }
  int cnt = lo2 - lo;
  float inv = 1.0f / (float)(cnt > 1 ? cnt : 1);
  __syncthreads();
  if (c < L) {
    float a = 0.f;
    for (int k = 0; k < 256; ++k) a += ts[k] * Wc[(size_t)k * L + c];
    out[(size_t)g * L + c] = a * inv + (cnt > 0 ? cb[c] : bl[c]);
  }
}

static inline size_t alignup(size_t v) { return (v + 255) & ~(size_t)255; }

extern "C" void kernel_launch(void* const* d_in, const int* in_sizes, int n_in,
                              void* d_out, int out_size, void* d_ws, size_t ws_size,
                              hipStream_t stream) {
  const float* x   = (const float*)d_in[0];
  const int*   src = (const int*)d_in[1];
  const int*   dst = (const int*)d_in[2];
  const int*   gid = (const int*)d_in[3];
  const float* W1  = (const float*)d_in[5];
  const float* b1  = (const float*)d_in[6];
  const float* W2  = (const float*)d_in[7];
  const float* b2  = (const float*)d_in[8];
  const float* Wl  = (const float*)d_in[9];
  const float* bl  = (const float*)d_in[10];
  float* out = (float*)d_out;

  const int N  = in_sizes[3];        // 50000
  const int E  = in_sizes[1];        // 800000
  const int L  = in_sizes[10];       // 50
  const int G  = out_size / L;       // 64
  const int RB = (N + 127) / 128;    // GEMM1 row blocks
  const int Npad = RB * 128;         // 50048
  const int NB = (Npad + 255) / 256; // tgemm K-chunks (196)
  const int NCH = 16;                // tred part-chunks

  char* p = (char*)d_ws;
  int*   outdeg8  = (int*)p;   p += alignup((size_t)8 * N * 4);
  int*   indeg8   = (int*)p;   p += alignup((size_t)8 * N * 4);
  float* Wg       = (float*)p; p += alignup((size_t)G * Npad * 4);
  float* t        = (float*)p; p += alignup((size_t)G * 256 * 4);
  int*   counter  = (int*)p;   p += 256;
  size_t zero_bytes = (size_t)(p - (char*)d_ws);
  int*   indeg_tot= (int*)p;   p += alignup((size_t)N * 4);
  int*   cursor8  = (int*)p;   p += alignup((size_t)8 * N * 4);
  float* cj       = (float*)p; p += alignup((size_t)N * 4);
  float* ci       = (float*)p; p += alignup((size_t)N * 4);
  int*   row_start= (int*)p;   p += alignup((size_t)N * 4);
  int*   csr_src  = (int*)p;   p += alignup((size_t)E * 4);
  unsigned short* xb   = (unsigned short*)p; p += alignup((size_t)Npad * 128 * 2);
  unsigned short* a1   = (unsigned short*)p; p += alignup((size_t)Npad * 128 * 2);
  unsigned short* h1t8 = (unsigned short*)p; p += alignup((size_t)Npad * 256 * 2);
  unsigned short* BT1  = (unsigned short*)p; p += alignup((size_t)256 * 128 * 2);
  float* tpart    = (float*)p; p += alignup((size_t)NB * 64 * 256 * 4);
  float* Wc       = (float*)p; p += alignup((size_t)256 * L * 4);
  float* cb       = (float*)p; p += alignup((size_t)L * 4);
  (void)ws_size; (void)n_in;

  hipMemsetAsync(d_ws, 0, zero_bytes, stream);

  k_degrees<<<(E + 255) / 256, 256, 0, stream>>>(src, dst, outdeg8, indeg8, E, N);
  k_norms<<<(N + 255) / 256, 256, 0, stream>>>(outdeg8, indeg8, cj, ci, indeg_tot,
                                               row_start, cursor8, counter, N);
  k_fill<<<(E + 255) / 256, 256, 0, stream>>>(src, dst, cursor8, csr_src, E, N);

  k_castT<<<(128 * 256 + 255) / 256, 256, 0, stream>>>(W1, BT1, 128, 256);
  k_cast_scale<<<(N * 128 / 4 + 255) / 256, 256, 0, stream>>>((const float4*)x, cj, xb,
                                                              N * 128 / 4);
  k_prep<<<257, 64, 0, stream>>>(W2, Wl, b2, bl, Wc, cb, L);

  k_spmm<<<N, 64, 0, stream>>>((const unsigned*)xb, row_start, indeg_tot, csr_src,
                               (unsigned*)a1, N);

  k_gemm_mfma<<<RB, 256, 0, stream>>>(a1, BT1, ci, b1, cj, h1t8, N);

  k_wgn2<<<8 * G, 256, 0, stream>>>(gid, ci, row_start, indeg_tot, csr_src, Wg, N, Npad, G);

  k_tgemm<<<NB, 256, 0, stream>>>(Wg, h1t8, tpart, Npad);

  k_tred<<<NCH * 64, 256, 0, stream>>>(tpart, t, NB, NCH);

  k_final2<<<G, 256, 0, stream>>>(t, gid, Wc, cb, bl, out, N, L);
}